// Round 6
// baseline (341.812 us; speedup 1.0000x reference)
//
#include <hip/hip_runtime.h>
#include <hip/hip_bf16.h>
#include <cstddef>
#include <cstdint>

// Problem constants
#define B 4
#define T 2048
#define C 1024
#define NQ 8
#define D 128
#define M_ROWS (B * T)          // 8192
#define NTOT (2 * D + NQ * D)   // 1280: [k | v | q0..q7]

typedef __bf16 bf16x8 __attribute__((ext_vector_type(8)));
typedef float  f32x4  __attribute__((ext_vector_type(4)));

__device__ __forceinline__ ushort f2bf(float f) {
    union { float f; uint32_t u; } v; v.f = f;
    const uint32_t r = (v.u + 0x7fffu + ((v.u >> 16) & 1u)) >> 16;
    return (ushort)r;
}

__device__ __forceinline__ void gld_lds16(const ushort* g, ushort* lds_uniform) {
    __builtin_amdgcn_global_load_lds(
        (const __attribute__((address_space(1))) void*)g,
        (__attribute__((address_space(3))) void*)lds_uniform, 16, 0, 0);
}

// -------------------- x f32 -> bf16 --------------------
__global__ __launch_bounds__(256) void xcvt(const float* __restrict__ x,
                                            ushort* __restrict__ xb) {
    const size_t i = ((size_t)blockIdx.x * 256 + threadIdx.x) * 8;
    const float4 a = *(const float4*)(x + i);
    const float4 b = *(const float4*)(x + i + 4);
    uint4 o;
    o.x = f2bf(a.x) | ((uint32_t)f2bf(a.y) << 16);
    o.y = f2bf(a.z) | ((uint32_t)f2bf(a.w) << 16);
    o.z = f2bf(b.x) | ((uint32_t)f2bf(b.y) << 16);
    o.w = f2bf(b.z) | ((uint32_t)f2bf(b.w) << 16);
    *(uint4*)(xb + i) = o;
}

// -------------------- weight transpose+convert: src f32 [1024][NC] -> dst bf16 [NC][1024]
__device__ __forceinline__ void wtrans_body(const float* __restrict__ src,
                                            ushort* __restrict__ dst, int NC,
                                            int bx, int by) {
    __shared__ ushort Ts[64][72];
    const int tid = threadIdx.x;
    const int k0 = by * 64, c0 = bx * 64;
    {
        const int r = tid >> 2, cq = tid & 3;
#pragma unroll
        for (int i = 0; i < 4; ++i) {
            const int cc = cq * 16 + i * 4;
            const float4 v = *(const float4*)(src + (size_t)(k0 + r) * NC + c0 + cc);
            uint2 o;
            o.x = f2bf(v.x) | ((uint32_t)f2bf(v.y) << 16);
            o.y = f2bf(v.z) | ((uint32_t)f2bf(v.w) << 16);
            *(uint2*)(&Ts[r][cc]) = o;
        }
    }
    __syncthreads();
    {
        const int n = tid >> 2, kq = tid & 3;
        ushort vv[16];
#pragma unroll
        for (int j = 0; j < 16; ++j) vv[j] = Ts[kq * 16 + j][n];
        uint4 o0, o1;
        o0.x = vv[0] | ((uint32_t)vv[1] << 16);  o0.y = vv[2] | ((uint32_t)vv[3] << 16);
        o0.z = vv[4] | ((uint32_t)vv[5] << 16);  o0.w = vv[6] | ((uint32_t)vv[7] << 16);
        o1.x = vv[8] | ((uint32_t)vv[9] << 16);  o1.y = vv[10] | ((uint32_t)vv[11] << 16);
        o1.z = vv[12] | ((uint32_t)vv[13] << 16); o1.w = vv[14] | ((uint32_t)vv[15] << 16);
        ushort* d = dst + (size_t)(c0 + n) * C + k0 + kq * 16;
        *(uint4*)d = o0;
        *(uint4*)(d + 8) = o1;
    }
}

// z: 0 -> Wk (rows 0..127), 1 -> Wv (128..255), 2..9 -> Wq[h] (256+128h..)
__global__ __launch_bounds__(256) void wtrans_qkv(const float* __restrict__ Wk,
                                                  const float* __restrict__ Wv,
                                                  const float* __restrict__ Wq,
                                                  ushort* __restrict__ WcatT) {
    const int z = blockIdx.z;
    const float* src;
    int rbase;
    if (z == 0)      { src = Wk; rbase = 0; }
    else if (z == 1) { src = Wv; rbase = D; }
    else             { src = Wq + (size_t)(z - 2) * C * D; rbase = 2 * D + (z - 2) * D; }
    wtrans_body(src, WcatT + (size_t)rbase * C, D, blockIdx.x, blockIdx.y);
}

__global__ __launch_bounds__(256) void wtrans_p(const float* __restrict__ Wp,
                                                ushort* __restrict__ WpT) {
    wtrans_body(Wp, WpT, C, blockIdx.x, blockIdx.y);
}

// -------------------- v transpose with per-32-key interleave permutation -----
// vb rows are qkv[row][D..2D); out vbT[d][g*32 + pi(k)], pi(k) = (k&15)*2 + (k>>4)
__global__ __launch_bounds__(256) void vtrans(const ushort* __restrict__ qkv,
                                              ushort* __restrict__ vbT) {
    __shared__ ushort Ts[64][136];
    const int tid = threadIdx.x;
    const int kb0 = blockIdx.x * 64;
    {
        const int r = tid >> 2, cq = tid & 3;
        const ushort* src = qkv + (size_t)(kb0 + r) * NTOT + D;
#pragma unroll
        for (int i = 0; i < 4; ++i) {
            const int cc = (cq * 4 + i) * 8;
            *(uint4*)(&Ts[r][cc]) = *(const uint4*)(src + cc);
        }
    }
    __syncthreads();
    {
        const int d = tid >> 1, half = tid & 1;
        ushort vv[32];
#pragma unroll
        for (int k = 0; k < 32; ++k) vv[k] = Ts[half * 32 + k][d];
        uint32_t dw[16];
#pragma unroll
        for (int i = 0; i < 16; ++i) dw[i] = vv[i] | ((uint32_t)vv[16 + i] << 16);
        uint32_t* dst = (uint32_t*)(vbT + (size_t)d * M_ROWS + kb0 + half * 32);
#pragma unroll
        for (int i = 0; i < 4; ++i)
            *(uint4*)(dst + i * 4) = *(uint4*)(&dw[i * 4]);
    }
}

// -------------------- MFMA GEMM: A bf16 [M][1024] @ Bt bf16 [N][1024]^T -----
// 128x128 tile, BK=32, 4 waves each computing 64x64 (4x4 16x16x32 MFMAs).
template <bool BF16_OUT>
__global__ __launch_bounds__(256) void gemm_mfma(const ushort* __restrict__ A,
                                                 const ushort* __restrict__ Bt,
                                                 void* __restrict__ Cout,
                                                 const float* __restrict__ bias,
                                                 const int Nout) {
    __shared__ ushort As[128 * 32];
    __shared__ ushort Bs[128 * 32];
    const int tid  = threadIdx.x;
    const int lane = tid & 63;
    const int w    = tid >> 6;
    const int col  = lane & 15;
    const int quad = lane >> 4;
    const int row0 = blockIdx.y * 128;
    const int col0 = blockIdx.x * 128;
    const int wm = w & 1, wn = w >> 1;

    const int srow = lane >> 2;         // staging row within 16-row chunk
    const int skk  = (lane & 3) * 8;    // staging k offset (ushorts)

    f32x4 acc[4][4];
#pragma unroll
    for (int i = 0; i < 4; ++i)
#pragma unroll
        for (int j = 0; j < 4; ++j) acc[i][j] = (f32x4){0.f, 0.f, 0.f, 0.f};

    for (int k0 = 0; k0 < C; k0 += 32) {
        __syncthreads();
#pragma unroll
        for (int j = 0; j < 2; ++j) {
            const int ci = w * 2 + j;              // LDS chunk 0..7 (1KB each)
            const int r  = ci * 16 + srow;         // tile row 0..127
            gld_lds16(A  + (size_t)(row0 + r) * C + k0 + skk, &As[ci * 512]);
            gld_lds16(Bt + (size_t)(col0 + r) * C + k0 + skk, &Bs[ci * 512]);
        }
        __syncthreads();

        bf16x8 af[4], bfr[4];
#pragma unroll
        for (int i = 0; i < 4; ++i)
            af[i] = *(const bf16x8*)&As[(wm * 64 + i * 16 + col) * 32 + quad * 8];
#pragma unroll
        for (int j = 0; j < 4; ++j)
            bfr[j] = *(const bf16x8*)&Bs[(wn * 64 + j * 16 + col) * 32 + quad * 8];
#pragma unroll
        for (int i = 0; i < 4; ++i)
#pragma unroll
            for (int j = 0; j < 4; ++j)
                acc[i][j] = __builtin_amdgcn_mfma_f32_16x16x32_bf16(af[i], bfr[j], acc[i][j], 0, 0, 0);
    }

#pragma unroll
    for (int i = 0; i < 4; ++i) {
#pragma unroll
        for (int r = 0; r < 4; ++r) {
            const int grow = row0 + wm * 64 + i * 16 + quad * 4 + r;
#pragma unroll
            for (int j = 0; j < 4; ++j) {
                const int gcol = col0 + wn * 64 + j * 16 + col;
                const float v = acc[i][j][r];
                if (BF16_OUT) {
                    ((ushort*)Cout)[(size_t)grow * Nout + gcol] = f2bf(v);
                } else {
                    ((float*)Cout)[(size_t)grow * Nout + gcol] = v + bias[gcol];
                }
            }
        }
    }
}

// -------------------- MFMA flash attention --------------------
// v3: 64-key tiles, no-max exact softmax, 2 heads per block (shared K/V),
// VGPR-prefetch software pipeline (global loads for tile it+1 overlap compute
// of tile it; ds_write_b128 staging replaces the barrier-drained gld_lds).
// qkv: [M_ROWS][NTOT] bf16 (k|v|q), vbT: [D][M_ROWS] bf16 (per-32-key permuted),
// attb out: [M_ROWS][C] bf16 (row = b*T+t, col = h*D+d)
__global__ __launch_bounds__(256, 2) void attn_mfma(const ushort* __restrict__ qkv,
                                                    const ushort* __restrict__ vbT,
                                                    ushort* __restrict__ attb) {
    __shared__ ushort Ks4[4][64][32];      // [d-chunk][key][32 d]   16 KB
    __shared__ ushort Vt4[4][128][16];     // [key-chunk][d][16 key] 16 KB
    __shared__ ushort Pt[4][2][2][16][32]; // [wave][head][grp][row][32 pkeys] 16 KB

    const int tid  = threadIdx.x;
    const int lane = tid & 63;
    const int w    = tid >> 6;
    const int col  = lane & 15;
    const int quad = lane >> 4;
    const int qb_i = (gridDim.x - 1) - blockIdx.x;   // longest blocks first
    const int h0   = blockIdx.y * 2;
    const int b    = blockIdx.z;
    const int q0   = qb_i * 64;
    const int myq  = q0 + w * 16 + col;

    bf16x8 qf[2][4];
#pragma unroll
    for (int hd = 0; hd < 2; ++hd) {
        const ushort* qrow = qkv + (size_t)(b * T + myq) * NTOT + 2 * D + (h0 + hd) * D;
#pragma unroll
        for (int kb2 = 0; kb2 < 4; ++kb2)
            qf[hd][kb2] = *(const bf16x8*)(qrow + kb2 * 32 + quad * 8);
    }

    const ushort* kbase = qkv + (size_t)b * T * NTOT;   // k at col 0
    const ushort* vbase = vbT + (size_t)b * T;          // row stride M_ROWS

    f32x4 O[2][8];
#pragma unroll
    for (int hd = 0; hd < 2; ++hd)
#pragma unroll
        for (int i = 0; i < 8; ++i) O[hd][i] = (f32x4){0.f, 0.f, 0.f, 0.f};
    float l_r[2][4] = {};

    const int ntiles = qb_i + 1;
    const int sk_key = lane >> 2;          // 0..15
    const int sk_d   = (lane & 3) * 8;
    const int sv_half = (lane & 1) * 8;

    uint4 kpre[4], vpre[4];

    // prefetch helpers: identical data placement as the old gld_lds (lane*16B)
    auto load_tile = [&](int s0) {
#pragma unroll
        for (int kg = 0; kg < 4; ++kg)
            kpre[kg] = *(const uint4*)(kbase + (size_t)(s0 + kg * 16 + sk_key) * NTOT + w * 32 + sk_d);
#pragma unroll
        for (int i2 = 0; i2 < 4; ++i2) {
            const int d = (i2 * 64 + lane) >> 1;
            vpre[i2] = *(const uint4*)(vbase + (size_t)d * M_ROWS + s0 + w * 16 + sv_half);
        }
    };
    auto store_tile = [&]() {
#pragma unroll
        for (int kg = 0; kg < 4; ++kg)
            *(uint4*)(&Ks4[w][kg * 16][0] + (size_t)lane * 8) = kpre[kg];
#pragma unroll
        for (int i2 = 0; i2 < 4; ++i2)
            *(uint4*)(&Vt4[w][i2 * 32][0] + (size_t)lane * 8) = vpre[i2];
    };

    load_tile(0);
    store_tile();
    __syncthreads();

    for (int it = 0; it < ntiles; ++it) {
        const int s0 = it * 64;
        const bool more = (it + 1 < ntiles);
        if (more) load_tile(s0 + 64);      // overlaps compute below

        // per head: S = Q K^T, exp, pack P
#pragma unroll
        for (int hd = 0; hd < 2; ++hd) {
            f32x4 S[4];
#pragma unroll
            for (int sub = 0; sub < 4; ++sub) {
                f32x4 a = (f32x4){0.f, 0.f, 0.f, 0.f};
#pragma unroll
                for (int kb2 = 0; kb2 < 4; ++kb2) {
                    bf16x8 kf = *(const bf16x8*)(&Ks4[kb2][sub * 16 + col][quad * 8]);
                    a = __builtin_amdgcn_mfma_f32_16x16x32_bf16(qf[hd][kb2], kf, a, 0, 0, 0);
                }
                S[sub] = a;
            }
#pragma unroll
            for (int r = 0; r < 4; ++r) {
                const int qq = q0 + w * 16 + quad * 4 + r;
                float p[4];
#pragma unroll
                for (int sub = 0; sub < 4; ++sub) {
                    const int key = s0 + sub * 16 + col;
                    const float s = (key > qq) ? -1e30f : S[sub][r] * 0.03125f;
                    p[sub] = __expf(s);
                }
                l_r[hd][r] += (p[0] + p[1]) + (p[2] + p[3]);
                *(uint32_t*)(&Pt[w][hd][0][quad * 4 + r][col * 2]) =
                    f2bf(p[0]) | ((uint32_t)f2bf(p[1]) << 16);
                *(uint32_t*)(&Pt[w][hd][1][quad * 4 + r][col * 2]) =
                    f2bf(p[2]) | ((uint32_t)f2bf(p[3]) << 16);
            }
        }

        // O += P V  (V fragments shared across both heads)
        bf16x8 pa[2][2];
#pragma unroll
        for (int hd = 0; hd < 2; ++hd) {
            pa[hd][0] = *(const bf16x8*)(&Pt[w][hd][0][col][quad * 8]);
            pa[hd][1] = *(const bf16x8*)(&Pt[w][hd][1][col][quad * 8]);
        }
        const int kg0 = quad >> 1;
        const int ko  = (quad & 1) * 8;
#pragma unroll
        for (int nt = 0; nt < 8; ++nt) {
            bf16x8 vf0 = *(const bf16x8*)(&Vt4[kg0][nt * 16 + col][ko]);
            bf16x8 vf1 = *(const bf16x8*)(&Vt4[2 + kg0][nt * 16 + col][ko]);
            O[0][nt] = __builtin_amdgcn_mfma_f32_16x16x32_bf16(pa[0][0], vf0, O[0][nt], 0, 0, 0);
            O[0][nt] = __builtin_amdgcn_mfma_f32_16x16x32_bf16(pa[0][1], vf1, O[0][nt], 0, 0, 0);
            O[1][nt] = __builtin_amdgcn_mfma_f32_16x16x32_bf16(pa[1][0], vf0, O[1][nt], 0, 0, 0);
            O[1][nt] = __builtin_amdgcn_mfma_f32_16x16x32_bf16(pa[1][1], vf1, O[1][nt], 0, 0, 0);
        }

        if (more) {
            __syncthreads();               // all waves done reading K/V LDS
            store_tile();
            __syncthreads();               // staged tile visible to all waves
        }
    }

    // epilogue: reduce l over the 16-lane col group (once), divide, store bf16
#pragma unroll
    for (int hd = 0; hd < 2; ++hd) {
#pragma unroll
        for (int r = 0; r < 4; ++r) {
            float s = l_r[hd][r];
#pragma unroll
            for (int off = 1; off < 16; off <<= 1) s += __shfl_xor(s, off);
            const float inv = 1.0f / s;
            const int t = q0 + w * 16 + quad * 4 + r;
            ushort* orow = attb + (size_t)(b * T + t) * C + (h0 + hd) * D;
#pragma unroll
            for (int nt = 0; nt < 8; ++nt) orow[nt * 16 + col] = f2bf(O[hd][nt][r] * inv);
        }
    }
}

// -------------------- Launch --------------------
extern "C" void kernel_launch(void* const* d_in, const int* in_sizes, int n_in,
                              void* d_out, int out_size, void* d_ws, size_t ws_size,
                              hipStream_t stream) {
    const float* x  = (const float*)d_in[0];
    const float* Wk = (const float*)d_in[1];
    const float* Wv = (const float*)d_in[2];
    const float* Wq = (const float*)d_in[3];
    const float* Wp = (const float*)d_in[4];
    const float* bp = (const float*)d_in[5];
    float* out = (float*)d_out;

    char* ws = (char*)d_ws;
    ushort* xb    = (ushort*)ws;                                  // 16 MB (aliased by attb later)
    ushort* attb  = xb;
    ushort* qkv   = (ushort*)(ws + (size_t)16  * 1024 * 1024);    // 20 MB
    ushort* WcatT = (ushort*)(ws + (size_t)36  * 1024 * 1024);    // 2.5 MB
    ushort* WpT   = (ushort*)(ws + (size_t)39  * 1024 * 1024);    // 2 MB
    ushort* vbT   = (ushort*)(ws + (size_t)41  * 1024 * 1024);    // 2 MB

    // 1) conversions
    xcvt<<<(size_t)M_ROWS * C / (256 * 8), 256, 0, stream>>>(x, xb);
    wtrans_qkv<<<dim3(D / 64, C / 64, 2 + NQ), 256, 0, stream>>>(Wk, Wv, Wq, WcatT);
    wtrans_p<<<dim3(C / 64, C / 64), 256, 0, stream>>>(Wp, WpT);

    // 2) fused QKV GEMM: [8192,1024] @ [1024,1280] -> qkv bf16
    gemm_mfma<true><<<dim3(NTOT / 128, M_ROWS / 128), 256, 0, stream>>>(
        xb, WcatT, qkv, nullptr, NTOT);

    // 3) v transpose (with key permutation)
    vtrans<<<M_ROWS / 64, 256, 0, stream>>>(qkv, vbT);

    // 4) flash attention (2 heads/block, VGPR-prefetch pipeline)
    attn_mfma<<<dim3(T / 64, NQ / 2, B), 256, 0, stream>>>(qkv, vbT, attb);

    // 5) projection: [8192,1024] @ [1024,1024] + bp -> out f32
    gemm_mfma<false><<<dim3(C / 128, M_ROWS / 128), 256, 0, stream>>>(
        attb, WpT, out, bp, C);
}

// Round 7
// 306.039 us; speedup vs baseline: 1.1169x; 1.1169x over previous
//
#include <hip/hip_runtime.h>
#include <hip/hip_bf16.h>
#include <cstddef>
#include <cstdint>

// Problem constants
#define B 4
#define T 2048
#define C 1024
#define NQ 8
#define D 128
#define M_ROWS (B * T)          // 8192
#define NTOT (2 * D + NQ * D)   // 1280: [k | v | q0..q7]

typedef __bf16 bf16x8 __attribute__((ext_vector_type(8)));
typedef float  f32x4  __attribute__((ext_vector_type(4)));
typedef float  f32x16 __attribute__((ext_vector_type(16)));

__device__ __forceinline__ ushort f2bf(float f) {
    union { float f; uint32_t u; } v; v.f = f;
    const uint32_t r = (v.u + 0x7fffu + ((v.u >> 16) & 1u)) >> 16;
    return (ushort)r;
}

__device__ __forceinline__ void gld_lds16(const ushort* g, ushort* lds_uniform) {
    __builtin_amdgcn_global_load_lds(
        (const __attribute__((address_space(1))) void*)g,
        (__attribute__((address_space(3))) void*)lds_uniform, 16, 0, 0);
}

// -------------------- x f32 -> bf16 --------------------
__global__ __launch_bounds__(256) void xcvt(const float* __restrict__ x,
                                            ushort* __restrict__ xb) {
    const size_t i = ((size_t)blockIdx.x * 256 + threadIdx.x) * 8;
    const float4 a = *(const float4*)(x + i);
    const float4 b = *(const float4*)(x + i + 4);
    uint4 o;
    o.x = f2bf(a.x) | ((uint32_t)f2bf(a.y) << 16);
    o.y = f2bf(a.z) | ((uint32_t)f2bf(a.w) << 16);
    o.z = f2bf(b.x) | ((uint32_t)f2bf(b.y) << 16);
    o.w = f2bf(b.z) | ((uint32_t)f2bf(b.w) << 16);
    *(uint4*)(xb + i) = o;
}

// -------------------- weight transpose+convert: src f32 [1024][NC] -> dst bf16 [NC][1024]
__device__ __forceinline__ void wtrans_body(const float* __restrict__ src,
                                            ushort* __restrict__ dst, int NC,
                                            int bx, int by) {
    __shared__ ushort Ts[64][72];
    const int tid = threadIdx.x;
    const int k0 = by * 64, c0 = bx * 64;
    {
        const int r = tid >> 2, cq = tid & 3;
#pragma unroll
        for (int i = 0; i < 4; ++i) {
            const int cc = cq * 16 + i * 4;
            const float4 v = *(const float4*)(src + (size_t)(k0 + r) * NC + c0 + cc);
            uint2 o;
            o.x = f2bf(v.x) | ((uint32_t)f2bf(v.y) << 16);
            o.y = f2bf(v.z) | ((uint32_t)f2bf(v.w) << 16);
            *(uint2*)(&Ts[r][cc]) = o;
        }
    }
    __syncthreads();
    {
        const int n = tid >> 2, kq = tid & 3;
        ushort vv[16];
#pragma unroll
        for (int j = 0; j < 16; ++j) vv[j] = Ts[kq * 16 + j][n];
        uint4 o0, o1;
        o0.x = vv[0] | ((uint32_t)vv[1] << 16);  o0.y = vv[2] | ((uint32_t)vv[3] << 16);
        o0.z = vv[4] | ((uint32_t)vv[5] << 16);  o0.w = vv[6] | ((uint32_t)vv[7] << 16);
        o1.x = vv[8] | ((uint32_t)vv[9] << 16);  o1.y = vv[10] | ((uint32_t)vv[11] << 16);
        o1.z = vv[12] | ((uint32_t)vv[13] << 16); o1.w = vv[14] | ((uint32_t)vv[15] << 16);
        ushort* d = dst + (size_t)(c0 + n) * C + k0 + kq * 16;
        *(uint4*)d = o0;
        *(uint4*)(d + 8) = o1;
    }
}

// z: 0 -> Wk (rows 0..127), 1 -> Wv (128..255), 2..9 -> Wq[h] (256+128h..)
__global__ __launch_bounds__(256) void wtrans_qkv(const float* __restrict__ Wk,
                                                  const float* __restrict__ Wv,
                                                  const float* __restrict__ Wq,
                                                  ushort* __restrict__ WcatT) {
    const int z = blockIdx.z;
    const float* src;
    int rbase;
    if (z == 0)      { src = Wk; rbase = 0; }
    else if (z == 1) { src = Wv; rbase = D; }
    else             { src = Wq + (size_t)(z - 2) * C * D; rbase = 2 * D + (z - 2) * D; }
    wtrans_body(src, WcatT + (size_t)rbase * C, D, blockIdx.x, blockIdx.y);
}

__global__ __launch_bounds__(256) void wtrans_p(const float* __restrict__ Wp,
                                                ushort* __restrict__ WpT) {
    wtrans_body(Wp, WpT, C, blockIdx.x, blockIdx.y);
}

// -------------------- v transpose (plain): vbT[d][b*T + key] --------------------
__global__ __launch_bounds__(256) void vtrans(const ushort* __restrict__ qkv,
                                              ushort* __restrict__ vbT) {
    __shared__ ushort Ts[64][136];
    const int tid = threadIdx.x;
    const int kb0 = blockIdx.x * 64;
    {
        const int r = tid >> 2, cq = tid & 3;
        const ushort* src = qkv + (size_t)(kb0 + r) * NTOT + D;
#pragma unroll
        for (int i = 0; i < 4; ++i) {
            const int cc = (cq * 4 + i) * 8;
            *(uint4*)(&Ts[r][cc]) = *(const uint4*)(src + cc);
        }
    }
    __syncthreads();
    {
        const int d = tid >> 1, half = tid & 1;
        ushort vv[32];
#pragma unroll
        for (int k = 0; k < 32; ++k) vv[k] = Ts[half * 32 + k][d];
        uint32_t dw[16];
#pragma unroll
        for (int i = 0; i < 16; ++i) dw[i] = vv[2 * i] | ((uint32_t)vv[2 * i + 1] << 16);
        uint32_t* dst = (uint32_t*)(vbT + (size_t)d * M_ROWS + kb0 + half * 32);
#pragma unroll
        for (int i = 0; i < 4; ++i)
            *(uint4*)(dst + i * 4) = *(uint4*)(&dw[i * 4]);
    }
}

// -------------------- MFMA GEMM: A bf16 [M][1024] @ Bt bf16 [N][1024]^T -----
template <bool BF16_OUT>
__global__ __launch_bounds__(256) void gemm_mfma(const ushort* __restrict__ A,
                                                 const ushort* __restrict__ Bt,
                                                 void* __restrict__ Cout,
                                                 const float* __restrict__ bias,
                                                 const int Nout) {
    __shared__ ushort As[128 * 32];
    __shared__ ushort Bs[128 * 32];
    const int tid  = threadIdx.x;
    const int lane = tid & 63;
    const int w    = tid >> 6;
    const int col  = lane & 15;
    const int quad = lane >> 4;
    const int row0 = blockIdx.y * 128;
    const int col0 = blockIdx.x * 128;
    const int wm = w & 1, wn = w >> 1;

    const int srow = lane >> 2;
    const int skk  = (lane & 3) * 8;

    f32x4 acc[4][4];
#pragma unroll
    for (int i = 0; i < 4; ++i)
#pragma unroll
        for (int j = 0; j < 4; ++j) acc[i][j] = (f32x4){0.f, 0.f, 0.f, 0.f};

    for (int k0 = 0; k0 < C; k0 += 32) {
        __syncthreads();
#pragma unroll
        for (int j = 0; j < 2; ++j) {
            const int ci = w * 2 + j;
            const int r  = ci * 16 + srow;
            gld_lds16(A  + (size_t)(row0 + r) * C + k0 + skk, &As[ci * 512]);
            gld_lds16(Bt + (size_t)(col0 + r) * C + k0 + skk, &Bs[ci * 512]);
        }
        __syncthreads();

        bf16x8 af[4], bfr[4];
#pragma unroll
        for (int i = 0; i < 4; ++i)
            af[i] = *(const bf16x8*)&As[(wm * 64 + i * 16 + col) * 32 + quad * 8];
#pragma unroll
        for (int j = 0; j < 4; ++j)
            bfr[j] = *(const bf16x8*)&Bs[(wn * 64 + j * 16 + col) * 32 + quad * 8];
#pragma unroll
        for (int i = 0; i < 4; ++i)
#pragma unroll
            for (int j = 0; j < 4; ++j)
                acc[i][j] = __builtin_amdgcn_mfma_f32_16x16x32_bf16(af[i], bfr[j], acc[i][j], 0, 0, 0);
    }

#pragma unroll
    for (int i = 0; i < 4; ++i) {
#pragma unroll
        for (int r = 0; r < 4; ++r) {
            const int grow = row0 + wm * 64 + i * 16 + quad * 4 + r;
#pragma unroll
            for (int j = 0; j < 4; ++j) {
                const int gcol = col0 + wn * 64 + j * 16 + col;
                const float v = acc[i][j][r];
                if (BF16_OUT) {
                    ((ushort*)Cout)[(size_t)grow * Nout + gcol] = f2bf(v);
                } else {
                    ((float*)Cout)[(size_t)grow * Nout + gcol] = v + bias[gcol];
                }
            }
        }
    }
}

// -------------------- MFMA flash attention (v4: 32x32x16, S^T scheme) --------
// S^T = K Q^T so MFMA C-layout rows are KEYS: P^T packs to dword LDS writes and
// PV reads P as contiguous b128 A-frags. Chunked pad-free LDS layouts keep
// global_load_lds legal and bank-perfect. No-max exact softmax (|s|<16).
// QK wave roles: (kh = w&1 key-half, qh = w>>1 query-half).
// PV wave roles: (dh = w&1 d-half,  qh = w>>1 query-half).
__global__ __launch_bounds__(256) void attn_mfma(const ushort* __restrict__ qkv,
                                                 const ushort* __restrict__ vbT,
                                                 ushort* __restrict__ attb) {
    __shared__ ushort Ks[16][64][8];   // [d-chunk8][key][8 d]  16 KB
    __shared__ ushort Vt[8][128][8];   // [k-chunk8][d][8 k]    16 KB
    __shared__ ushort Pt[64][72];      // [q][k] stride 72 (16B-aligned rows) 9 KB
    __shared__ float  lred[4][32];

    const int tid  = threadIdx.x;
    const int lane = tid & 63;
    const int w    = tid >> 6;
    const int col  = lane & 31;
    const int lh   = lane >> 5;
    const int qb_i = (gridDim.x - 1) - blockIdx.x;   // longest blocks first
    const int h    = blockIdx.y;
    const int b    = blockIdx.z;
    const int q0   = qb_i * 64;
    const int qh   = w >> 1;           // query-half (QK and PV)
    const int kh   = w & 1;            // QK key-half
    const int dh   = w & 1;            // PV d-half

    // Q B-frags (B[k=d][n=query]): query = q0 + qh*32 + col, 8 d per frag
    const ushort* qrow = qkv + (size_t)(b * T + q0 + qh * 32 + col) * NTOT + 2 * D + h * D;
    bf16x8 qf[8];
#pragma unroll
    for (int dc = 0; dc < 8; ++dc)
        qf[dc] = *(const bf16x8*)(qrow + dc * 16 + lh * 8);

    const ushort* kbase = qkv + (size_t)b * T * NTOT;   // k at col 0
    const ushort* vbase = vbT + (size_t)b * T;          // row stride M_ROWS

    f32x16 O[2] = {};                  // [dt] -> d = dh*64 + dt*32 + col, rows=q
    float l_acc = 0.f;

    const int ntiles = qb_i + 1;

    for (int it = 0; it < ntiles; ++it) {
        const int s0 = it * 64;
        __syncthreads();               // prev tile LDS reads (Ks/Vt/Pt) done
        // stage K: 16 chunks (dc8) of 64 keys x 8 d; wave handles 4
#pragma unroll
        for (int i = 0; i < 4; ++i) {
            const int dc8 = w * 4 + i;
            gld_lds16(kbase + (size_t)(s0 + lane) * NTOT + dc8 * 8, &Ks[dc8][0][0]);
        }
        // stage V: 8 chunks (kc8) x 2 d-halves; wave handles 4 issues
#pragma unroll
        for (int i = 0; i < 4; ++i) {
            const int idx = w * 4 + i;
            const int kc8 = idx >> 1, dhalf = idx & 1;
            gld_lds16(vbase + (size_t)(dhalf * 64 + lane) * M_ROWS + s0 + kc8 * 8,
                      &Vt[kc8][dhalf * 64][0]);
        }
        __syncthreads();               // staged data visible

        // S^T quadrant = K[kh] . Q^T[qh]  (rows=keys, cols=queries)
        f32x16 S = {};
#pragma unroll
        for (int dc = 0; dc < 8; ++dc) {
            bf16x8 kf = *(const bf16x8*)&Ks[dc * 2 + lh][kh * 32 + col][0];
            S = __builtin_amdgcn_mfma_f32_32x32x16_bf16(kf, qf[dc], S, 0, 0, 0);
        }

        // exp + (mask only on the diagonal tile) + P^T dword-packed writes
        const bool masked = (it == ntiles - 1);
        const int q_l = qh * 32 + col;
#pragma unroll
        for (int g = 0; g < 4; ++g) {
            const int kb_l = kh * 32 + 8 * g + 4 * lh;
            float p[4];
            if (masked) {
#pragma unroll
                for (int rr = 0; rr < 4; ++rr) {
                    const float s = (kb_l + rr > q_l) ? -1e30f : S[4 * g + rr] * 0.03125f;
                    p[rr] = __expf(s);
                }
            } else {
#pragma unroll
                for (int rr = 0; rr < 4; ++rr) p[rr] = __expf(S[4 * g + rr] * 0.03125f);
            }
            l_acc += (p[0] + p[1]) + (p[2] + p[3]);
            *(uint32_t*)&Pt[q_l][kb_l]     = f2bf(p[0]) | ((uint32_t)f2bf(p[1]) << 16);
            *(uint32_t*)&Pt[q_l][kb_l + 2] = f2bf(p[2]) | ((uint32_t)f2bf(p[3]) << 16);
        }
        __syncthreads();               // full P tile visible

        // O += P V : A = P[q][k] (b128), B = V[k][d] (b128)
#pragma unroll
        for (int kc = 0; kc < 4; ++kc) {
            bf16x8 pf = *(const bf16x8*)&Pt[q_l][kc * 16 + lh * 8];
            bf16x8 vf0 = *(const bf16x8*)&Vt[kc * 2 + lh][dh * 64 + col][0];
            bf16x8 vf1 = *(const bf16x8*)&Vt[kc * 2 + lh][dh * 64 + 32 + col][0];
            O[0] = __builtin_amdgcn_mfma_f32_32x32x16_bf16(pf, vf0, O[0], 0, 0, 0);
            O[1] = __builtin_amdgcn_mfma_f32_32x32x16_bf16(pf, vf1, O[1], 0, 0, 0);
        }
    }

    // epilogue: l(q) = sum over lane halves + the two kh waves of the q-half
    l_acc += __shfl_xor(l_acc, 32);
    lred[w][col] = l_acc;
    __syncthreads();
    const float lfinv = 1.0f / (lred[qh * 2][col] + lred[qh * 2 + 1][col]);

#pragma unroll
    for (int g = 0; g < 4; ++g) {
#pragma unroll
        for (int rr = 0; rr < 4; ++rr) {
            const int row = 8 * g + 4 * lh + rr;               // q-local row
            const float inv = __shfl(lfinv, row);
            const int q = q0 + qh * 32 + row;
            ushort* orow = attb + (size_t)(b * T + q) * C + h * D + dh * 64;
            orow[col]      = f2bf(O[0][4 * g + rr] * inv);
            orow[32 + col] = f2bf(O[1][4 * g + rr] * inv);
        }
    }
}

// -------------------- Launch --------------------
extern "C" void kernel_launch(void* const* d_in, const int* in_sizes, int n_in,
                              void* d_out, int out_size, void* d_ws, size_t ws_size,
                              hipStream_t stream) {
    const float* x  = (const float*)d_in[0];
    const float* Wk = (const float*)d_in[1];
    const float* Wv = (const float*)d_in[2];
    const float* Wq = (const float*)d_in[3];
    const float* Wp = (const float*)d_in[4];
    const float* bp = (const float*)d_in[5];
    float* out = (float*)d_out;

    char* ws = (char*)d_ws;
    ushort* xb    = (ushort*)ws;                                  // 16 MB (aliased by attb later)
    ushort* attb  = xb;
    ushort* qkv   = (ushort*)(ws + (size_t)16  * 1024 * 1024);    // 20 MB
    ushort* WcatT = (ushort*)(ws + (size_t)36  * 1024 * 1024);    // 2.5 MB
    ushort* WpT   = (ushort*)(ws + (size_t)39  * 1024 * 1024);    // 2 MB
    ushort* vbT   = (ushort*)(ws + (size_t)41  * 1024 * 1024);    // 2 MB

    // 1) conversions
    xcvt<<<(size_t)M_ROWS * C / (256 * 8), 256, 0, stream>>>(x, xb);
    wtrans_qkv<<<dim3(D / 64, C / 64, 2 + NQ), 256, 0, stream>>>(Wk, Wv, Wq, WcatT);
    wtrans_p<<<dim3(C / 64, C / 64), 256, 0, stream>>>(Wp, WpT);

    // 2) fused QKV GEMM: [8192,1024] @ [1024,1280] -> qkv bf16
    gemm_mfma<true><<<dim3(NTOT / 128, M_ROWS / 128), 256, 0, stream>>>(
        xb, WcatT, qkv, nullptr, NTOT);

    // 3) v transpose
    vtrans<<<M_ROWS / 64, 256, 0, stream>>>(qkv, vbT);

    // 4) flash attention (32x32x16 MFMA, S^T scheme)
    attn_mfma<<<dim3(T / 64, NQ, B), 256, 0, stream>>>(qkv, vbT, attb);

    // 5) projection: [8192,1024] @ [1024,1024] + bp -> out f32
    gemm_mfma<false><<<dim3(C / 128, M_ROWS / 128), 256, 0, stream>>>(
        attb, WpT, out, bp, C);
}

// Round 8
// 249.940 us; speedup vs baseline: 1.3676x; 1.2244x over previous
//
#include <hip/hip_runtime.h>
#include <hip/hip_bf16.h>
#include <cstddef>
#include <cstdint>

// Problem constants
#define B 4
#define T 2048
#define C 1024
#define NQ 8
#define D 128
#define M_ROWS (B * T)          // 8192
#define NTOT (2 * D + NQ * D)   // 1280: [k | v | q0..q7]

typedef __bf16 bf16x8 __attribute__((ext_vector_type(8)));
typedef float  f32x4  __attribute__((ext_vector_type(4)));

__device__ __forceinline__ ushort f2bf(float f) {
    union { float f; uint32_t u; } v; v.f = f;
    const uint32_t r = (v.u + 0x7fffu + ((v.u >> 16) & 1u)) >> 16;
    return (ushort)r;
}

__device__ __forceinline__ void gld_lds16(const ushort* g, ushort* lds_uniform) {
    __builtin_amdgcn_global_load_lds(
        (const __attribute__((address_space(1))) void*)g,
        (__attribute__((address_space(3))) void*)lds_uniform, 16, 0, 0);
}

// -------------------- x f32 -> bf16 --------------------
__global__ __launch_bounds__(256) void xcvt(const float* __restrict__ x,
                                            ushort* __restrict__ xb) {
    const size_t i = ((size_t)blockIdx.x * 256 + threadIdx.x) * 8;
    const float4 a = *(const float4*)(x + i);
    const float4 b = *(const float4*)(x + i + 4);
    uint4 o;
    o.x = f2bf(a.x) | ((uint32_t)f2bf(a.y) << 16);
    o.y = f2bf(a.z) | ((uint32_t)f2bf(a.w) << 16);
    o.z = f2bf(b.x) | ((uint32_t)f2bf(b.y) << 16);
    o.w = f2bf(b.z) | ((uint32_t)f2bf(b.w) << 16);
    *(uint4*)(xb + i) = o;
}

// -------------------- weight transpose+convert: src f32 [1024][NC] -> dst bf16 [NC][1024]
__device__ __forceinline__ void wtrans_body(const float* __restrict__ src,
                                            ushort* __restrict__ dst, int NC,
                                            int bx, int by) {
    __shared__ ushort Ts[64][72];
    const int tid = threadIdx.x;
    const int k0 = by * 64, c0 = bx * 64;
    {
        const int r = tid >> 2, cq = tid & 3;
#pragma unroll
        for (int i = 0; i < 4; ++i) {
            const int cc = cq * 16 + i * 4;
            const float4 v = *(const float4*)(src + (size_t)(k0 + r) * NC + c0 + cc);
            uint2 o;
            o.x = f2bf(v.x) | ((uint32_t)f2bf(v.y) << 16);
            o.y = f2bf(v.z) | ((uint32_t)f2bf(v.w) << 16);
            *(uint2*)(&Ts[r][cc]) = o;
        }
    }
    __syncthreads();
    {
        const int n = tid >> 2, kq = tid & 3;
        ushort vv[16];
#pragma unroll
        for (int j = 0; j < 16; ++j) vv[j] = Ts[kq * 16 + j][n];
        uint4 o0, o1;
        o0.x = vv[0] | ((uint32_t)vv[1] << 16);  o0.y = vv[2] | ((uint32_t)vv[3] << 16);
        o0.z = vv[4] | ((uint32_t)vv[5] << 16);  o0.w = vv[6] | ((uint32_t)vv[7] << 16);
        o1.x = vv[8] | ((uint32_t)vv[9] << 16);  o1.y = vv[10] | ((uint32_t)vv[11] << 16);
        o1.z = vv[12] | ((uint32_t)vv[13] << 16); o1.w = vv[14] | ((uint32_t)vv[15] << 16);
        ushort* d = dst + (size_t)(c0 + n) * C + k0 + kq * 16;
        *(uint4*)d = o0;
        *(uint4*)(d + 8) = o1;
    }
}

// z: 0 -> Wk (rows 0..127), 1 -> Wv (128..255), 2..9 -> Wq[h] (256+128h..)
__global__ __launch_bounds__(256) void wtrans_qkv(const float* __restrict__ Wk,
                                                  const float* __restrict__ Wv,
                                                  const float* __restrict__ Wq,
                                                  ushort* __restrict__ WcatT) {
    const int z = blockIdx.z;
    const float* src;
    int rbase;
    if (z == 0)      { src = Wk; rbase = 0; }
    else if (z == 1) { src = Wv; rbase = D; }
    else             { src = Wq + (size_t)(z - 2) * C * D; rbase = 2 * D + (z - 2) * D; }
    wtrans_body(src, WcatT + (size_t)rbase * C, D, blockIdx.x, blockIdx.y);
}

__global__ __launch_bounds__(256) void wtrans_p(const float* __restrict__ Wp,
                                                ushort* __restrict__ WpT) {
    wtrans_body(Wp, WpT, C, blockIdx.x, blockIdx.y);
}

// -------------------- v transpose with per-32-key interleave permutation -----
// vb rows are qkv[row][D..2D); out vbT[d][g*32 + pi(k)], pi(k) = (k&15)*2 + (k>>4)
__global__ __launch_bounds__(256) void vtrans(const ushort* __restrict__ qkv,
                                              ushort* __restrict__ vbT) {
    __shared__ ushort Ts[64][136];
    const int tid = threadIdx.x;
    const int kb0 = blockIdx.x * 64;
    {
        const int r = tid >> 2, cq = tid & 3;
        const ushort* src = qkv + (size_t)(kb0 + r) * NTOT + D;
#pragma unroll
        for (int i = 0; i < 4; ++i) {
            const int cc = (cq * 4 + i) * 8;
            *(uint4*)(&Ts[r][cc]) = *(const uint4*)(src + cc);
        }
    }
    __syncthreads();
    {
        const int d = tid >> 1, half = tid & 1;
        ushort vv[32];
#pragma unroll
        for (int k = 0; k < 32; ++k) vv[k] = Ts[half * 32 + k][d];
        uint32_t dw[16];
#pragma unroll
        for (int i = 0; i < 16; ++i) dw[i] = vv[i] | ((uint32_t)vv[16 + i] << 16);
        uint32_t* dst = (uint32_t*)(vbT + (size_t)d * M_ROWS + kb0 + half * 32);
#pragma unroll
        for (int i = 0; i < 4; ++i)
            *(uint4*)(dst + i * 4) = *(uint4*)(&dw[i * 4]);
    }
}

// -------------------- MFMA GEMM: A bf16 [M][1024] @ Bt bf16 [N][1024]^T -----
template <bool BF16_OUT>
__global__ __launch_bounds__(256) void gemm_mfma(const ushort* __restrict__ A,
                                                 const ushort* __restrict__ Bt,
                                                 void* __restrict__ Cout,
                                                 const float* __restrict__ bias,
                                                 const int Nout) {
    __shared__ ushort As[128 * 32];
    __shared__ ushort Bs[128 * 32];
    const int tid  = threadIdx.x;
    const int lane = tid & 63;
    const int w    = tid >> 6;
    const int col  = lane & 15;
    const int quad = lane >> 4;
    const int row0 = blockIdx.y * 128;
    const int col0 = blockIdx.x * 128;
    const int wm = w & 1, wn = w >> 1;

    const int srow = lane >> 2;
    const int skk  = (lane & 3) * 8;

    f32x4 acc[4][4];
#pragma unroll
    for (int i = 0; i < 4; ++i)
#pragma unroll
        for (int j = 0; j < 4; ++j) acc[i][j] = (f32x4){0.f, 0.f, 0.f, 0.f};

    for (int k0 = 0; k0 < C; k0 += 32) {
        __syncthreads();
#pragma unroll
        for (int j = 0; j < 2; ++j) {
            const int ci = w * 2 + j;
            const int r  = ci * 16 + srow;
            gld_lds16(A  + (size_t)(row0 + r) * C + k0 + skk, &As[ci * 512]);
            gld_lds16(Bt + (size_t)(col0 + r) * C + k0 + skk, &Bs[ci * 512]);
        }
        __syncthreads();

        bf16x8 af[4], bfr[4];
#pragma unroll
        for (int i = 0; i < 4; ++i)
            af[i] = *(const bf16x8*)&As[(wm * 64 + i * 16 + col) * 32 + quad * 8];
#pragma unroll
        for (int j = 0; j < 4; ++j)
            bfr[j] = *(const bf16x8*)&Bs[(wn * 64 + j * 16 + col) * 32 + quad * 8];
#pragma unroll
        for (int i = 0; i < 4; ++i)
#pragma unroll
            for (int j = 0; j < 4; ++j)
                acc[i][j] = __builtin_amdgcn_mfma_f32_16x16x32_bf16(af[i], bfr[j], acc[i][j], 0, 0, 0);
    }

#pragma unroll
    for (int i = 0; i < 4; ++i) {
#pragma unroll
        for (int r = 0; r < 4; ++r) {
            const int grow = row0 + wm * 64 + i * 16 + quad * 4 + r;
#pragma unroll
            for (int j = 0; j < 4; ++j) {
                const int gcol = col0 + wn * 64 + j * 16 + col;
                const float v = acc[i][j][r];
                if (BF16_OUT) {
                    ((ushort*)Cout)[(size_t)grow * Nout + gcol] = f2bf(v);
                } else {
                    ((float*)Cout)[(size_t)grow * Nout + gcol] = v + bias[gcol];
                }
            }
        }
    }
}

// -------------------- MFMA flash attention (64-key tiles, no-max softmax) ---
// R5 structure (best measured) + balanced qb swizzle.
// Co-resident blocks on a CU are spaced 256 dispatch ids apart = same x, z+1.
// qb = (z odd) ? Xmax-x : x makes each z-parity pair sum to a constant 33
// tiles -> every CU gets equal work (was 4..128 block-tiles, 2x the mean).
__global__ __launch_bounds__(256) void attn_mfma(const ushort* __restrict__ qkv,
                                                 const ushort* __restrict__ vbT,
                                                 ushort* __restrict__ attb) {
    __shared__ ushort Ks4[4][64][32];    // [d-chunk][key][32 d]  16 KB, gld_lds layout
    __shared__ ushort Vt4[4][128][16];   // [key-chunk][d][16 keys] 16 KB, gld_lds layout
    __shared__ ushort Pt[4][2][16][32];  // [wave][key-group][q-row][32 permuted keys] 8 KB

    const int tid  = threadIdx.x;
    const int lane = tid & 63;
    const int w    = tid >> 6;
    const int col  = lane & 15;
    const int quad = lane >> 4;
    const int h    = blockIdx.y;
    const int b    = blockIdx.z;
    // balanced swizzle (see header comment)
    const int qb_i = (b & 1) ? (gridDim.x - 1 - blockIdx.x) : blockIdx.x;
    const int q0   = qb_i * 64;
    const int myq  = q0 + w * 16 + col;

    const ushort* qrow = qkv + (size_t)(b * T + myq) * NTOT + 2 * D + h * D;
    bf16x8 qf[4];
#pragma unroll
    for (int kb2 = 0; kb2 < 4; ++kb2)
        qf[kb2] = *(const bf16x8*)(qrow + kb2 * 32 + quad * 8);

    const ushort* kbase = qkv + (size_t)b * T * NTOT;   // k at col 0
    const ushort* vbase = vbT + (size_t)b * T;          // row stride M_ROWS

    f32x4 O[8];
#pragma unroll
    for (int i = 0; i < 8; ++i) O[i] = (f32x4){0.f, 0.f, 0.f, 0.f};
    float l_r[4] = {0.f, 0.f, 0.f, 0.f};

    const int ntiles = qb_i + 1;
    const int sk_key = lane >> 2;
    const int sk_d   = (lane & 3) * 8;
    const int sv_half = (lane & 1) * 8;

    for (int it = 0; it < ntiles; ++it) {
        const int s0 = it * 64;
        __syncthreads();
#pragma unroll
        for (int kg = 0; kg < 4; ++kg) {
            gld_lds16(kbase + (size_t)(s0 + kg * 16 + sk_key) * NTOT + w * 32 + sk_d,
                      &Ks4[w][kg * 16][0]);
        }
#pragma unroll
        for (int i2 = 0; i2 < 4; ++i2) {
            const int d = (i2 * 64 + lane) >> 1;
            gld_lds16(vbase + (size_t)d * M_ROWS + s0 + w * 16 + sv_half,
                      &Vt4[w][i2 * 32][0]);
        }
        __syncthreads();

        // S = Q K^T: 4 subtiles of 16 keys
        f32x4 S[4];
#pragma unroll
        for (int sub = 0; sub < 4; ++sub) {
            f32x4 a = (f32x4){0.f, 0.f, 0.f, 0.f};
#pragma unroll
            for (int kb2 = 0; kb2 < 4; ++kb2) {
                bf16x8 kf = *(const bf16x8*)(&Ks4[kb2][sub * 16 + col][quad * 8]);
                a = __builtin_amdgcn_mfma_f32_16x16x32_bf16(qf[kb2], kf, a, 0, 0, 0);
            }
            S[sub] = a;
        }

        // p = exp(scale*s) with causal mask; per-lane l partials; pack P.
#pragma unroll
        for (int r = 0; r < 4; ++r) {
            const int qq = q0 + w * 16 + quad * 4 + r;
            float p[4];
#pragma unroll
            for (int sub = 0; sub < 4; ++sub) {
                const int key = s0 + sub * 16 + col;
                const float s = (key > qq) ? -1e30f : S[sub][r] * 0.03125f;
                p[sub] = __expf(s);
            }
            l_r[r] += (p[0] + p[1]) + (p[2] + p[3]);
            *(uint32_t*)(&Pt[w][0][quad * 4 + r][col * 2]) =
                f2bf(p[0]) | ((uint32_t)f2bf(p[1]) << 16);
            *(uint32_t*)(&Pt[w][1][quad * 4 + r][col * 2]) =
                f2bf(p[2]) | ((uint32_t)f2bf(p[3]) << 16);
        }

        // O += P V  (P A-layout from per-wave LDS; V B-layout from chunked LDS)
        bf16x8 pa0 = *(const bf16x8*)(&Pt[w][0][col][quad * 8]);
        bf16x8 pa1 = *(const bf16x8*)(&Pt[w][1][col][quad * 8]);
        const int kg0 = quad >> 1;
        const int ko  = (quad & 1) * 8;
#pragma unroll
        for (int nt = 0; nt < 8; ++nt) {
            bf16x8 vf0 = *(const bf16x8*)(&Vt4[kg0][nt * 16 + col][ko]);
            bf16x8 vf1 = *(const bf16x8*)(&Vt4[2 + kg0][nt * 16 + col][ko]);
            O[nt] = __builtin_amdgcn_mfma_f32_16x16x32_bf16(pa0, vf0, O[nt], 0, 0, 0);
            O[nt] = __builtin_amdgcn_mfma_f32_16x16x32_bf16(pa1, vf1, O[nt], 0, 0, 0);
        }
    }

    // epilogue: reduce l over the 16-lane col group (once), divide, store bf16
#pragma unroll
    for (int r = 0; r < 4; ++r) {
        float s = l_r[r];
#pragma unroll
        for (int off = 1; off < 16; off <<= 1) s += __shfl_xor(s, off);
        const float inv = 1.0f / s;
        const int t = q0 + w * 16 + quad * 4 + r;
        ushort* orow = attb + (size_t)(b * T + t) * C + h * D;
#pragma unroll
        for (int nt = 0; nt < 8; ++nt) orow[nt * 16 + col] = f2bf(O[nt][r] * inv);
    }
}

// -------------------- Launch --------------------
extern "C" void kernel_launch(void* const* d_in, const int* in_sizes, int n_in,
                              void* d_out, int out_size, void* d_ws, size_t ws_size,
                              hipStream_t stream) {
    const float* x  = (const float*)d_in[0];
    const float* Wk = (const float*)d_in[1];
    const float* Wv = (const float*)d_in[2];
    const float* Wq = (const float*)d_in[3];
    const float* Wp = (const float*)d_in[4];
    const float* bp = (const float*)d_in[5];
    float* out = (float*)d_out;

    char* ws = (char*)d_ws;
    ushort* xb    = (ushort*)ws;                                  // 16 MB (aliased by attb later)
    ushort* attb  = xb;
    ushort* qkv   = (ushort*)(ws + (size_t)16  * 1024 * 1024);    // 20 MB
    ushort* WcatT = (ushort*)(ws + (size_t)36  * 1024 * 1024);    // 2.5 MB
    ushort* WpT   = (ushort*)(ws + (size_t)39  * 1024 * 1024);    // 2 MB
    ushort* vbT   = (ushort*)(ws + (size_t)41  * 1024 * 1024);    // 2 MB

    // 1) conversions
    xcvt<<<(size_t)M_ROWS * C / (256 * 8), 256, 0, stream>>>(x, xb);
    wtrans_qkv<<<dim3(D / 64, C / 64, 2 + NQ), 256, 0, stream>>>(Wk, Wv, Wq, WcatT);
    wtrans_p<<<dim3(C / 64, C / 64), 256, 0, stream>>>(Wp, WpT);

    // 2) fused QKV GEMM: [8192,1024] @ [1024,1280] -> qkv bf16
    gemm_mfma<true><<<dim3(NTOT / 128, M_ROWS / 128), 256, 0, stream>>>(
        xb, WcatT, qkv, nullptr, NTOT);

    // 3) v transpose (with key permutation)
    vtrans<<<M_ROWS / 64, 256, 0, stream>>>(qkv, vbT);

    // 4) flash attention (R5 structure + balanced qb swizzle)
    attn_mfma<<<dim3(T / 64, NQ, B), 256, 0, stream>>>(qkv, vbT, attb);

    // 5) projection: [8192,1024] @ [1024,1024] + bp -> out f32
    gemm_mfma<false><<<dim3(C / 128, M_ROWS / 128), 256, 0, stream>>>(
        attb, WpT, out, bp, C);
}